// Round 6
// baseline (238.455 us; speedup 1.0000x reference)
//
#include <hip/hip_runtime.h>
#include <math.h>

#define SB   2
#define SEQ  2048
#define FDIM 1024
#define NH   16
#define HD   64
#define BH   (SB * NH)   // 32
#define LK   72          // attention LDS row stride in f16 elems (64 + 8 pad)

typedef _Float16 half8 __attribute__((ext_vector_type(8)));
typedef __attribute__((ext_vector_type(4))) float floatx4;

#if __has_builtin(__builtin_amdgcn_exp2f)
#define EXP2(x) __builtin_amdgcn_exp2f(x)
#else
#define EXP2(x) __expf(0.6931471805599453f * (x))
#endif

__device__ __forceinline__ unsigned pk_f16(float a, float b) {
    unsigned short ha = __builtin_bit_cast(unsigned short, (_Float16)a);
    unsigned short hb = __builtin_bit_cast(unsigned short, (_Float16)b);
    return (unsigned)ha | ((unsigned)hb << 16);
}
__device__ __forceinline__ unsigned short f16_1(float a) {
    _Float16 h = (_Float16)a;
    return __builtin_bit_cast(unsigned short, h);
}
__device__ __forceinline__ void load16_lds(const unsigned short* g, unsigned short* l) {
    __builtin_amdgcn_global_load_lds(
        (const __attribute__((address_space(1))) unsigned int*)g,
        (__attribute__((address_space(3))) unsigned int*)l, 16, 0, 0);
}

// ---------------------------------------------------------------------------
// Fused conversions: blocks [0,4096) activations fp32->f16;
// blocks [4096,5120) weight transpose+convert W[K][N]fp32 -> Wt[N][K]f16.
// ---------------------------------------------------------------------------
__global__ __launch_bounds__(256) void cvt_all(
    const float* __restrict__ in0, const float* __restrict__ in1,
    unsigned short* __restrict__ out0, unsigned short* __restrict__ out1,
    const float* __restrict__ Wq, const float* __restrict__ Wkv,
    const float* __restrict__ Wo, unsigned short* __restrict__ Wqt,
    unsigned short* __restrict__ Wkvt, unsigned short* __restrict__ Wot)
{
    const int tid = threadIdx.x;
    int bx = blockIdx.x;
    if (bx < 4096) {
        const float* in = (bx < 2048) ? in0 : in1;
        unsigned short* out = (bx < 2048) ? out0 : out1;
        int i = ((bx & 2047) * 256 + tid) * 8;
        float4 a = *(const float4*)(in + i);
        float4 b = *(const float4*)(in + i + 4);
        uint4 o;
        o.x = pk_f16(a.x, a.y); o.y = pk_f16(a.z, a.w);
        o.z = pk_f16(b.x, b.y); o.w = pk_f16(b.z, b.w);
        *(uint4*)(out + i) = o;
        return;
    }
    __shared__ float T[64 * 65];
    int id = bx - 4096;
    const float* W; unsigned short* Wt; int N, n0, k0;
    if (id < 256)      { W = Wq;  Wt = Wqt;  N = 1024; n0 = (id & 15) << 6; k0 = (id >> 4) << 6; }
    else if (id < 768) { id -= 256; W = Wkv; Wt = Wkvt; N = 2048; n0 = (id & 31) << 6; k0 = (id >> 5) << 6; }
    else               { id -= 768; W = Wo;  Wt = Wot;  N = 1024; n0 = (id & 15) << 6; k0 = (id >> 4) << 6; }

    #pragma unroll
    for (int i = 0; i < 4; ++i) {
        int idx = tid + (i << 8);
        int row = idx >> 4, c4 = idx & 15;
        float4 v = *(const float4*)(W + (size_t)(k0 + row) * N + n0 + (c4 << 2));
        float* tp = &T[row * 65 + (c4 << 2)];
        tp[0] = v.x; tp[1] = v.y; tp[2] = v.z; tp[3] = v.w;
    }
    __syncthreads();
    #pragma unroll
    for (int i = 0; i < 4; ++i) {
        int idx = tid + (i << 8);
        int n = idx >> 4, c4 = idx & 15;
        float x = T[(c4 * 4 + 0) * 65 + n];
        float y = T[(c4 * 4 + 1) * 65 + n];
        float z = T[(c4 * 4 + 2) * 65 + n];
        float w = T[(c4 * 4 + 3) * 65 + n];
        uint2 o = make_uint2(pk_f16(x, y), pk_f16(z, w));
        *(uint2*)(Wt + (size_t)(n0 + n) * FDIM + k0 + (c4 << 2)) = o;
    }
}

// ---------------------------------------------------------------------------
// f16 MFMA GEMM core (m97 structure): acc = A @ Wt^T, 128x128 tile, BK=32.
// ---------------------------------------------------------------------------
__device__ __forceinline__ void gemm_core(
    const unsigned short* __restrict__ A, const unsigned short* __restrict__ Wt,
    int m0, int n0, int K, floatx4 (&acc)[4][4],
    unsigned short* Al, unsigned short* Bl)
{
    const int tid  = threadIdx.x;
    const int w    = tid >> 6;
    const int lane = tid & 63;
    const int q    = lane >> 4, l = lane & 15;
    const int wm = (w >> 1) * 64, wn = (w & 1) * 64;

    for (int k0 = 0; k0 < K; k0 += 32) {
        __syncthreads();
        #pragma unroll
        for (int it = 0; it < 2; ++it) {
            int c = (w * 2 + it) * 64 + lane;
            int row = c >> 2, o = (c & 3) * 8;
            load16_lds(A  + (size_t)(m0 + row) * K + k0 + o, Al + c * 8);
            load16_lds(Wt + (size_t)(n0 + row) * K + k0 + o, Bl + c * 8);
        }
        __syncthreads();

        half8 aF[4], bF[4];
        #pragma unroll
        for (int i = 0; i < 4; ++i)
            aF[i] = *(const half8*)(Al + (wm + 16 * i + l) * 32 + 8 * q);
        #pragma unroll
        for (int j = 0; j < 4; ++j)
            bF[j] = *(const half8*)(Bl + (wn + 16 * j + l) * 32 + 8 * q);
        #pragma unroll
        for (int i = 0; i < 4; ++i)
            #pragma unroll
            for (int j = 0; j < 4; ++j)
                acc[i][j] = __builtin_amdgcn_mfma_f32_16x16x32_f16(
                    aF[i], bF[j], acc[i][j], 0, 0, 0);
    }
}

// ---------------------------------------------------------------------------
// Merged Q + KV projection GEMM. grid (24, 32): bx<8 -> Q, else KV.
// Q output is PRE-SCALED by log2(e) so attention can use exp2 directly.
// ---------------------------------------------------------------------------
__global__ __launch_bounds__(256) void gemm_qkv(
    const unsigned short* __restrict__ Af, const unsigned short* __restrict__ At,
    const unsigned short* __restrict__ Wqt, const unsigned short* __restrict__ Wkvt,
    const float* __restrict__ bq, const float* __restrict__ bkv,
    unsigned short* __restrict__ Qo, unsigned short* __restrict__ Ko,
    unsigned short* __restrict__ Vo)
{
    __shared__ unsigned short Al[128 * 32];
    __shared__ unsigned short Bl[128 * 32];

    const int tid  = threadIdx.x;
    const int w    = tid >> 6;
    const int lane = tid & 63;
    const int q    = lane >> 4, l = lane & 15;
    const int wm = (w >> 1) * 64, wn = (w & 1) * 64;
    const int m0 = blockIdx.y * 128;

    bool isQ = blockIdx.x < 8;
    const unsigned short* A  = isQ ? Af : At;
    const unsigned short* Wt = isQ ? Wqt : Wkvt;
    const float* bias        = isQ ? bq : bkv;
    const int n0 = (isQ ? blockIdx.x : (blockIdx.x - 8)) * 128;

    floatx4 acc[4][4];
    #pragma unroll
    for (int i = 0; i < 4; ++i)
        #pragma unroll
        for (int j = 0; j < 4; ++j)
            acc[i][j] = (floatx4){0.f, 0.f, 0.f, 0.f};

    gemm_core(A, Wt, m0, n0, FDIM, acc, Al, Bl);

    float bj[4];
    #pragma unroll
    for (int j = 0; j < 4; ++j) bj[j] = bias[n0 + wn + 16 * j + l];

    const float qscale = isQ ? 1.4426950408889634f : 1.0f;

    #pragma unroll
    for (int i = 0; i < 4; ++i)
        #pragma unroll
        for (int j = 0; j < 4; ++j) {
            int n = n0 + wn + 16 * j + l;
            #pragma unroll
            for (int r = 0; r < 4; ++r) {
                int m = m0 + wm + 16 * i + 4 * q + r;
                float v = (acc[i][j][r] + bj[j]) * qscale;
                int b = m >> 11, s = m & (SEQ - 1);
                if (isQ) {
                    int h = n >> 6, dd = n & 63;
                    Qo[((size_t)(b * NH + h) * SEQ + s) * HD + dd] = f16_1(v);
                } else {
                    int np = (n < FDIM) ? n : (n - FDIM);
                    unsigned short* Cd = (n < FDIM) ? Ko : Vo;
                    int h = np >> 6, dd = np & 63;
                    Cd[((size_t)(b * NH + h) * SEQ + s) * HD + dd] = f16_1(v);
                }
            }
        }
}

// ---------------------------------------------------------------------------
// Out-projection GEMM: 64x128 tile -> 512 blocks (2/CU) so inter-block
// overlap hides the barrier drain (old 256-block version was 1/CU).
// Wave w owns m 0..63 x n [32w, 32w+32): acc[4][2].
// ---------------------------------------------------------------------------
__global__ __launch_bounds__(256) void gemm_out(
    const unsigned short* __restrict__ A, const unsigned short* __restrict__ Wt,
    const float* __restrict__ bias, float* __restrict__ C)
{
    __shared__ unsigned short Al[64 * 32];    // 4 KB
    __shared__ unsigned short Bl[128 * 32];   // 8 KB

    const int tid  = threadIdx.x;
    const int w    = tid >> 6;
    const int lane = tid & 63;
    const int q    = lane >> 4, l = lane & 15;
    const int m0 = blockIdx.y * 64, n0 = blockIdx.x * 128;
    const int wn = 32 * w;

    floatx4 acc[4][2];
    #pragma unroll
    for (int i = 0; i < 4; ++i)
        #pragma unroll
        for (int j = 0; j < 2; ++j)
            acc[i][j] = (floatx4){0.f, 0.f, 0.f, 0.f};

    for (int k0 = 0; k0 < FDIM; k0 += 32) {
        __syncthreads();
        {
            int row = tid >> 2, o = (tid & 3) * 8;            // A: 256 chunks
            load16_lds(A + (size_t)(m0 + row) * FDIM + k0 + o, Al + tid * 8);
        }
        #pragma unroll
        for (int it = 0; it < 2; ++it) {                      // B: 512 chunks
            int c = tid + (it << 8);
            int row = c >> 2, o = (c & 3) * 8;
            load16_lds(Wt + (size_t)(n0 + row) * FDIM + k0 + o, Bl + c * 8);
        }
        __syncthreads();

        half8 aF[4], bF[2];
        #pragma unroll
        for (int i = 0; i < 4; ++i)
            aF[i] = *(const half8*)(Al + (16 * i + l) * 32 + 8 * q);
        #pragma unroll
        for (int j = 0; j < 2; ++j)
            bF[j] = *(const half8*)(Bl + (wn + 16 * j + l) * 32 + 8 * q);
        #pragma unroll
        for (int i = 0; i < 4; ++i)
            #pragma unroll
            for (int j = 0; j < 2; ++j)
                acc[i][j] = __builtin_amdgcn_mfma_f32_16x16x32_f16(
                    aF[i], bF[j], acc[i][j], 0, 0, 0);
    }

    float bj[2];
    #pragma unroll
    for (int j = 0; j < 2; ++j) bj[j] = bias[n0 + wn + 16 * j + l];

    #pragma unroll
    for (int i = 0; i < 4; ++i)
        #pragma unroll
        for (int j = 0; j < 2; ++j) {
            int n = n0 + wn + 16 * j + l;
            #pragma unroll
            for (int r = 0; r < 4; ++r) {
                int m = m0 + 16 * i + 4 * q + r;
                C[(size_t)m * FDIM + n] = acc[i][j][r] + bj[j];
            }
        }
}

// ---------------------------------------------------------------------------
// V [bh][z][d] f16 -> Vt [bh][d][z] f16
// ---------------------------------------------------------------------------
__global__ __launch_bounds__(256) void transpose_v(
    const unsigned short* __restrict__ V, unsigned short* __restrict__ Vt)
{
    __shared__ unsigned short T[64 * 72];
    const int tid = threadIdx.x;
    const int zt = blockIdx.x & 31, bh = blockIdx.x >> 5;
    const int z0 = zt << 6;
    #pragma unroll
    for (int it = 0; it < 2; ++it) {
        int idx = tid + (it << 8);
        int row = idx >> 3, c8 = idx & 7;
        *(half8*)(&T[row * 72 + c8 * 8]) =
            *(const half8*)(V + ((size_t)bh * SEQ + z0 + row) * HD + c8 * 8);
    }
    __syncthreads();
    #pragma unroll
    for (int it = 0; it < 4; ++it) {
        int idx = tid + (it << 8);
        int d = idx >> 4, c4 = idx & 15;
        unsigned short a = T[(c4 * 4 + 0) * 72 + d];
        unsigned short b = T[(c4 * 4 + 1) * 72 + d];
        unsigned short c = T[(c4 * 4 + 2) * 72 + d];
        unsigned short e = T[(c4 * 4 + 3) * 72 + d];
        uint2 o = make_uint2((unsigned)a | ((unsigned)b << 16),
                             (unsigned)c | ((unsigned)e << 16));
        *(uint2*)(Vt + ((size_t)bh * HD + d) * SEQ + z0 + (c4 << 2)) = o;
    }
}

// ---------------------------------------------------------------------------
// Flash attention, f16 MFMA, fp32 softmax in log2 domain (Q pre-scaled).
// Interior tiles (zt < st, st>=1) skip the mask entirely (provably unmasked).
// Row sums via ones-MFMA. Row 0 masked to 0.0f -> exact uniform softmax.
// ---------------------------------------------------------------------------
__global__ __launch_bounds__(256) void attn_kernel(
    const unsigned short* __restrict__ Qg, const unsigned short* __restrict__ Kg,
    const unsigned short* __restrict__ Vtg, unsigned short* __restrict__ Og)
{
    __shared__ unsigned short Kl[64 * LK];
    __shared__ unsigned short Vl[64 * LK];
    __shared__ unsigned short Pl[4 * 16 * LK];

    const int tid  = threadIdx.x;
    const int w    = tid >> 6;
    const int lane = tid & 63;
    const int q    = lane >> 4;
    const int l    = lane & 15;

    const int bid = blockIdx.x;
    const int bh  = bid & (BH - 1);
    const int t_o = bid >> 5;                      // heavy tiles first
    const int st  = (t_o == 0) ? 0 : (32 - t_o);
    const int s0  = st << 6;

    const unsigned short* Qb  = Qg  + (size_t)bh * SEQ * HD;
    const unsigned short* Kb  = Kg  + (size_t)bh * SEQ * HD;
    const unsigned short* Vtb = Vtg + (size_t)bh * HD * SEQ;

    half8 aQ[2];
    {
        const unsigned short* qp = Qb + (size_t)(s0 + 16 * w + l) * HD + 8 * q;
        aQ[0] = *(const half8*)(qp);
        aQ[1] = *(const half8*)(qp + 32);
    }

    half8 ones;
    #pragma unroll
    for (int j = 0; j < 8; ++j) ones[j] = (_Float16)1.0f;

    float m_run[4], l_run[4];
    floatx4 oacc[4];
    #pragma unroll
    for (int r = 0; r < 4; ++r) { m_run[r] = -INFINITY; l_run[r] = 0.f; }
    #pragma unroll
    for (int nd = 0; nd < 4; ++nd) oacc[nd] = (floatx4){0.f, 0.f, 0.f, 0.f};

    const int ntiles = (st == 0) ? (SEQ >> 6) : (st + 1);

    for (int zt = 0; zt < ntiles; ++zt) {
        const int z0 = zt << 6;
        __syncthreads();
        #pragma unroll
        for (int it = 0; it < 2; ++it) {
            int idx = tid + (it << 8);
            int row = idx >> 3, c8 = idx & 7;
            *(half8*)(&Kl[row * LK + c8 * 8]) =
                *(const half8*)(Kb + (size_t)(z0 + row) * HD + c8 * 8);
            *(half8*)(&Vl[row * LK + c8 * 8]) =
                *(const half8*)(Vtb + (size_t)row * SEQ + z0 + c8 * 8);
        }
        __syncthreads();

        floatx4 sacc[4];
        #pragma unroll
        for (int t = 0; t < 4; ++t) {
            sacc[t] = (floatx4){0.f, 0.f, 0.f, 0.f};
            half8 b0 = *(const half8*)(&Kl[(16 * t + l) * LK + 8 * q]);
            half8 b1 = *(const half8*)(&Kl[(16 * t + l) * LK + 8 * q + 32]);
            sacc[t] = __builtin_amdgcn_mfma_f32_16x16x32_f16(aQ[0], b0, sacc[t], 0, 0, 0);
            sacc[t] = __builtin_amdgcn_mfma_f32_16x16x32_f16(aQ[1], b1, sacc[t], 0, 0, 0);
        }

        // mask only on the diagonal tile (or everywhere for the st==0 block);
        // interior tiles zt<st are provably unmasked (z0+63 < s0).
        if (st == 0 || zt == st) {
            #pragma unroll
            for (int t = 0; t < 4; ++t) {
                int z = z0 + 16 * t + l;
                #pragma unroll
                for (int r = 0; r < 4; ++r) {
                    int s = s0 + 16 * w + 4 * q + r;
                    if (z >= s) sacc[t][r] = (s == 0) ? 0.0f : -1e12f;
                }
            }
        }

        // row max (16-lane shuffle); exp2 in fp32 (logits already log2-scaled)
        float alpha[4];
        #pragma unroll
        for (int r = 0; r < 4; ++r) {
            float rm = fmaxf(fmaxf(sacc[0][r], sacc[1][r]),
                             fmaxf(sacc[2][r], sacc[3][r]));
            rm = fmaxf(rm, __shfl_xor(rm, 1, 64));
            rm = fmaxf(rm, __shfl_xor(rm, 2, 64));
            rm = fmaxf(rm, __shfl_xor(rm, 4, 64));
            rm = fmaxf(rm, __shfl_xor(rm, 8, 64));
            float mn = fmaxf(m_run[r], rm);
            #pragma unroll
            for (int t = 0; t < 4; ++t)
                sacc[t][r] = EXP2(sacc[t][r] - mn);
            alpha[r] = EXP2(m_run[r] - mn);
            m_run[r] = mn;
            #pragma unroll
            for (int nd = 0; nd < 4; ++nd) oacc[nd][r] *= alpha[r];
        }

        // P -> per-wave LDS strip as f16 (same-wave write->read, no barrier)
        unsigned short* Pw = &Pl[w * 16 * LK];
        #pragma unroll
        for (int t = 0; t < 4; ++t)
            #pragma unroll
            for (int r = 0; r < 4; ++r)
                Pw[(4 * q + r) * LK + 16 * t + l] = f16_1(sacc[t][r]);

        half8 aP0 = *(const half8*)(&Pw[l * LK + 8 * q]);
        half8 aP1 = *(const half8*)(&Pw[l * LK + 8 * q + 32]);

        // row sums via ones-MFMA
        floatx4 ls = (floatx4){0.f, 0.f, 0.f, 0.f};
        ls = __builtin_amdgcn_mfma_f32_16x16x32_f16(aP0, ones, ls, 0, 0, 0);
        ls = __builtin_amdgcn_mfma_f32_16x16x32_f16(aP1, ones, ls, 0, 0, 0);
        #pragma unroll
        for (int r = 0; r < 4; ++r)
            l_run[r] = alpha[r] * l_run[r] + ls[r];

        // O += P @ V
        #pragma unroll
        for (int nd = 0; nd < 4; ++nd) {
            half8 b0 = *(const half8*)(&Vl[(16 * nd + l) * LK + 8 * q]);
            half8 b1 = *(const half8*)(&Vl[(16 * nd + l) * LK + 8 * q + 32]);
            oacc[nd] = __builtin_amdgcn_mfma_f32_16x16x32_f16(aP0, b0, oacc[nd], 0, 0, 0);
            oacc[nd] = __builtin_amdgcn_mfma_f32_16x16x32_f16(aP1, b1, oacc[nd], 0, 0, 0);
        }
    }

    // epilogue: O/l -> f16 [B*S][F] row-major (A operand of out-GEMM)
    const int b = bh >> 4, h = bh & 15;
    #pragma unroll
    for (int r = 0; r < 4; ++r) {
        float inv = 1.0f / l_run[r];
        int s = s0 + 16 * w + 4 * q + r;
        unsigned short* op = Og + ((size_t)b * SEQ + s) * FDIM + h * HD;
        #pragma unroll
        for (int nd = 0; nd < 4; ++nd)
            op[16 * nd + l] = f16_1(oacc[nd][r] * inv);
    }
}

// ---------------------------------------------------------------------------
extern "C" void kernel_launch(void* const* d_in, const int* in_sizes, int n_in,
                              void* d_out, int out_size, void* d_ws, size_t ws_size,
                              hipStream_t stream) {
    const float* attend_from = (const float*)d_in[0];
    const float* attend_to   = (const float*)d_in[1];
    const float* w_q   = (const float*)d_in[2];
    const float* b_q   = (const float*)d_in[3];
    const float* w_kv  = (const float*)d_in[4];
    const float* b_kv  = (const float*)d_in[5];
    const float* w_out = (const float*)d_in[6];
    const float* b_out = (const float*)d_in[7];
    float* out = (float*)d_out;

    unsigned short* ws = (unsigned short*)d_ws;
    const size_t E = (size_t)(SB * SEQ) * FDIM;   // 4M elems
    unsigned short* Af   = ws;
    unsigned short* At   = ws + E;
    unsigned short* Qb   = ws + 2 * E;
    unsigned short* Kb   = ws + 3 * E;
    unsigned short* Vb   = ws + 4 * E;
    unsigned short* Vt   = ws + 5 * E;
    unsigned short* Ob   = Vb;                    // reuse V after transpose
    unsigned short* Wqt  = ws + 6 * E;
    unsigned short* Wkvt = ws + 6 * E + E / 4;
    unsigned short* Wot  = ws + 6 * E + E / 4 + E / 2;

    dim3 blk(256);
    const int M = SB * SEQ;   // 4096

    cvt_all<<<dim3(5120), blk, 0, stream>>>(
        attend_from, attend_to, Af, At, w_q, w_kv, w_out, Wqt, Wkvt, Wot);
    gemm_qkv<<<dim3(24, M / 128), blk, 0, stream>>>(
        Af, At, Wqt, Wkvt, b_q, b_kv, Qb, Kb, Vb);
    transpose_v<<<dim3(BH * (SEQ / 64)), blk, 0, stream>>>(Vb, Vt);
    attn_kernel<<<dim3(BH * (SEQ / 64)), blk, 0, stream>>>(Qb, Kb, Vt, Ob);
    gemm_out<<<dim3(FDIM / 128, M / 64), blk, 0, stream>>>(Ob, Wot, b_out, out);
}

// Round 7
// 234.937 us; speedup vs baseline: 1.0150x; 1.0150x over previous
//
#include <hip/hip_runtime.h>
#include <math.h>

#define SB   2
#define SEQ  2048
#define FDIM 1024
#define NH   16
#define HD   64
#define BH   (SB * NH)   // 32
#define LK   72          // attention LDS row stride in f16 elems (64 + 8 pad)

typedef _Float16 half8 __attribute__((ext_vector_type(8)));
typedef _Float16 half4 __attribute__((ext_vector_type(4)));
typedef __attribute__((ext_vector_type(4))) float floatx4;

#if __has_builtin(__builtin_amdgcn_exp2f)
#define EXP2(x) __builtin_amdgcn_exp2f(x)
#else
#define EXP2(x) __expf(0.6931471805599453f * (x))
#endif

__device__ __forceinline__ unsigned pk_f16(float a, float b) {
    unsigned short ha = __builtin_bit_cast(unsigned short, (_Float16)a);
    unsigned short hb = __builtin_bit_cast(unsigned short, (_Float16)b);
    return (unsigned)ha | ((unsigned)hb << 16);
}
__device__ __forceinline__ unsigned short f16_1(float a) {
    _Float16 h = (_Float16)a;
    return __builtin_bit_cast(unsigned short, h);
}
__device__ __forceinline__ void load16_lds(const unsigned short* g, unsigned short* l) {
    __builtin_amdgcn_global_load_lds(
        (const __attribute__((address_space(1))) unsigned int*)g,
        (__attribute__((address_space(3))) unsigned int*)l, 16, 0, 0);
}

// ---------------------------------------------------------------------------
// Fused conversions: blocks [0,4096) activations fp32->f16;
// blocks [4096,5120) weight transpose+convert W[K][N]fp32 -> Wt[N][K]f16.
// ---------------------------------------------------------------------------
__global__ __launch_bounds__(256) void cvt_all(
    const float* __restrict__ in0, const float* __restrict__ in1,
    unsigned short* __restrict__ out0, unsigned short* __restrict__ out1,
    const float* __restrict__ Wq, const float* __restrict__ Wkv,
    const float* __restrict__ Wo, unsigned short* __restrict__ Wqt,
    unsigned short* __restrict__ Wkvt, unsigned short* __restrict__ Wot)
{
    const int tid = threadIdx.x;
    int bx = blockIdx.x;
    if (bx < 4096) {
        const float* in = (bx < 2048) ? in0 : in1;
        unsigned short* out = (bx < 2048) ? out0 : out1;
        int i = ((bx & 2047) * 256 + tid) * 8;
        float4 a = *(const float4*)(in + i);
        float4 b = *(const float4*)(in + i + 4);
        uint4 o;
        o.x = pk_f16(a.x, a.y); o.y = pk_f16(a.z, a.w);
        o.z = pk_f16(b.x, b.y); o.w = pk_f16(b.z, b.w);
        *(uint4*)(out + i) = o;
        return;
    }
    __shared__ float T[64 * 65];
    int id = bx - 4096;
    const float* W; unsigned short* Wt; int N, n0, k0;
    if (id < 256)      { W = Wq;  Wt = Wqt;  N = 1024; n0 = (id & 15) << 6; k0 = (id >> 4) << 6; }
    else if (id < 768) { id -= 256; W = Wkv; Wt = Wkvt; N = 2048; n0 = (id & 31) << 6; k0 = (id >> 5) << 6; }
    else               { id -= 768; W = Wo;  Wt = Wot;  N = 1024; n0 = (id & 15) << 6; k0 = (id >> 4) << 6; }

    #pragma unroll
    for (int i = 0; i < 4; ++i) {
        int idx = tid + (i << 8);
        int row = idx >> 4, c4 = idx & 15;
        float4 v = *(const float4*)(W + (size_t)(k0 + row) * N + n0 + (c4 << 2));
        float* tp = &T[row * 65 + (c4 << 2)];
        tp[0] = v.x; tp[1] = v.y; tp[2] = v.z; tp[3] = v.w;
    }
    __syncthreads();
    #pragma unroll
    for (int i = 0; i < 4; ++i) {
        int idx = tid + (i << 8);
        int n = idx >> 4, c4 = idx & 15;
        float x = T[(c4 * 4 + 0) * 65 + n];
        float y = T[(c4 * 4 + 1) * 65 + n];
        float z = T[(c4 * 4 + 2) * 65 + n];
        float w = T[(c4 * 4 + 3) * 65 + n];
        uint2 o = make_uint2(pk_f16(x, y), pk_f16(z, w));
        *(uint2*)(Wt + (size_t)(n0 + n) * FDIM + k0 + (c4 << 2)) = o;
    }
}

// ---------------------------------------------------------------------------
// f16 MFMA GEMM core (m97 structure): acc = A @ Wt^T, 128x128 tile, BK=32.
// ---------------------------------------------------------------------------
__device__ __forceinline__ void gemm_core(
    const unsigned short* __restrict__ A, const unsigned short* __restrict__ Wt,
    int m0, int n0, int K, floatx4 (&acc)[4][4],
    unsigned short* Al, unsigned short* Bl)
{
    const int tid  = threadIdx.x;
    const int w    = tid >> 6;
    const int lane = tid & 63;
    const int q    = lane >> 4, l = lane & 15;
    const int wm = (w >> 1) * 64, wn = (w & 1) * 64;

    for (int k0 = 0; k0 < K; k0 += 32) {
        __syncthreads();
        #pragma unroll
        for (int it = 0; it < 2; ++it) {
            int c = (w * 2 + it) * 64 + lane;
            int row = c >> 2, o = (c & 3) * 8;
            load16_lds(A  + (size_t)(m0 + row) * K + k0 + o, Al + c * 8);
            load16_lds(Wt + (size_t)(n0 + row) * K + k0 + o, Bl + c * 8);
        }
        __syncthreads();

        half8 aF[4], bF[4];
        #pragma unroll
        for (int i = 0; i < 4; ++i)
            aF[i] = *(const half8*)(Al + (wm + 16 * i + l) * 32 + 8 * q);
        #pragma unroll
        for (int j = 0; j < 4; ++j)
            bF[j] = *(const half8*)(Bl + (wn + 16 * j + l) * 32 + 8 * q);
        #pragma unroll
        for (int i = 0; i < 4; ++i)
            #pragma unroll
            for (int j = 0; j < 4; ++j)
                acc[i][j] = __builtin_amdgcn_mfma_f32_16x16x32_f16(
                    aF[i], bF[j], acc[i][j], 0, 0, 0);
    }
}

// ---------------------------------------------------------------------------
// Merged Q + KV projection GEMM. grid (24, 32): bx<8 -> Q, else KV.
// Q output is PRE-SCALED by log2(e) so attention can use exp2 directly.
// ---------------------------------------------------------------------------
__global__ __launch_bounds__(256) void gemm_qkv(
    const unsigned short* __restrict__ Af, const unsigned short* __restrict__ At,
    const unsigned short* __restrict__ Wqt, const unsigned short* __restrict__ Wkvt,
    const float* __restrict__ bq, const float* __restrict__ bkv,
    unsigned short* __restrict__ Qo, unsigned short* __restrict__ Ko,
    unsigned short* __restrict__ Vo)
{
    __shared__ unsigned short Al[128 * 32];
    __shared__ unsigned short Bl[128 * 32];

    const int tid  = threadIdx.x;
    const int w    = tid >> 6;
    const int lane = tid & 63;
    const int q    = lane >> 4, l = lane & 15;
    const int wm = (w >> 1) * 64, wn = (w & 1) * 64;
    const int m0 = blockIdx.y * 128;

    bool isQ = blockIdx.x < 8;
    const unsigned short* A  = isQ ? Af : At;
    const unsigned short* Wt = isQ ? Wqt : Wkvt;
    const float* bias        = isQ ? bq : bkv;
    const int n0 = (isQ ? blockIdx.x : (blockIdx.x - 8)) * 128;

    floatx4 acc[4][4];
    #pragma unroll
    for (int i = 0; i < 4; ++i)
        #pragma unroll
        for (int j = 0; j < 4; ++j)
            acc[i][j] = (floatx4){0.f, 0.f, 0.f, 0.f};

    gemm_core(A, Wt, m0, n0, FDIM, acc, Al, Bl);

    float bj[4];
    #pragma unroll
    for (int j = 0; j < 4; ++j) bj[j] = bias[n0 + wn + 16 * j + l];

    const float qscale = isQ ? 1.4426950408889634f : 1.0f;

    #pragma unroll
    for (int i = 0; i < 4; ++i)
        #pragma unroll
        for (int j = 0; j < 4; ++j) {
            int n = n0 + wn + 16 * j + l;
            #pragma unroll
            for (int r = 0; r < 4; ++r) {
                int m = m0 + wm + 16 * i + 4 * q + r;
                float v = (acc[i][j][r] + bj[j]) * qscale;
                int b = m >> 11, s = m & (SEQ - 1);
                if (isQ) {
                    int h = n >> 6, dd = n & 63;
                    Qo[((size_t)(b * NH + h) * SEQ + s) * HD + dd] = f16_1(v);
                } else {
                    int np = (n < FDIM) ? n : (n - FDIM);
                    unsigned short* Cd = (n < FDIM) ? Ko : Vo;
                    int h = np >> 6, dd = np & 63;
                    Cd[((size_t)(b * NH + h) * SEQ + s) * HD + dd] = f16_1(v);
                }
            }
        }
}

// ---------------------------------------------------------------------------
// Out-projection GEMM: 64x128 tile, 512 blocks (2/CU hides barrier drain).
// ---------------------------------------------------------------------------
__global__ __launch_bounds__(256) void gemm_out(
    const unsigned short* __restrict__ A, const unsigned short* __restrict__ Wt,
    const float* __restrict__ bias, float* __restrict__ C)
{
    __shared__ unsigned short Al[64 * 32];    // 4 KB
    __shared__ unsigned short Bl[128 * 32];   // 8 KB

    const int tid  = threadIdx.x;
    const int w    = tid >> 6;
    const int lane = tid & 63;
    const int q    = lane >> 4, l = lane & 15;
    const int m0 = blockIdx.y * 64, n0 = blockIdx.x * 128;
    const int wn = 32 * w;

    floatx4 acc[4][2];
    #pragma unroll
    for (int i = 0; i < 4; ++i)
        #pragma unroll
        for (int j = 0; j < 2; ++j)
            acc[i][j] = (floatx4){0.f, 0.f, 0.f, 0.f};

    for (int k0 = 0; k0 < FDIM; k0 += 32) {
        __syncthreads();
        {
            int row = tid >> 2, o = (tid & 3) * 8;
            load16_lds(A + (size_t)(m0 + row) * FDIM + k0 + o, Al + tid * 8);
        }
        #pragma unroll
        for (int it = 0; it < 2; ++it) {
            int c = tid + (it << 8);
            int row = c >> 2, o = (c & 3) * 8;
            load16_lds(Wt + (size_t)(n0 + row) * FDIM + k0 + o, Bl + c * 8);
        }
        __syncthreads();

        half8 aF[4], bF[2];
        #pragma unroll
        for (int i = 0; i < 4; ++i)
            aF[i] = *(const half8*)(Al + (16 * i + l) * 32 + 8 * q);
        #pragma unroll
        for (int j = 0; j < 2; ++j)
            bF[j] = *(const half8*)(Bl + (wn + 16 * j + l) * 32 + 8 * q);
        #pragma unroll
        for (int i = 0; i < 4; ++i)
            #pragma unroll
            for (int j = 0; j < 2; ++j)
                acc[i][j] = __builtin_amdgcn_mfma_f32_16x16x32_f16(
                    aF[i], bF[j], acc[i][j], 0, 0, 0);
    }

    float bj[2];
    #pragma unroll
    for (int j = 0; j < 2; ++j) bj[j] = bias[n0 + wn + 16 * j + l];

    #pragma unroll
    for (int i = 0; i < 4; ++i)
        #pragma unroll
        for (int j = 0; j < 2; ++j) {
            int n = n0 + wn + 16 * j + l;
            #pragma unroll
            for (int r = 0; r < 4; ++r) {
                int m = m0 + 16 * i + 4 * q + r;
                C[(size_t)m * FDIM + n] = acc[i][j][r] + bj[j];
            }
        }
}

// ---------------------------------------------------------------------------
// V [bh][z][d] f16 -> Vt [bh][d][z] f16
// ---------------------------------------------------------------------------
__global__ __launch_bounds__(256) void transpose_v(
    const unsigned short* __restrict__ V, unsigned short* __restrict__ Vt)
{
    __shared__ unsigned short T[64 * 72];
    const int tid = threadIdx.x;
    const int zt = blockIdx.x & 31, bh = blockIdx.x >> 5;
    const int z0 = zt << 6;
    #pragma unroll
    for (int it = 0; it < 2; ++it) {
        int idx = tid + (it << 8);
        int row = idx >> 3, c8 = idx & 7;
        *(half8*)(&T[row * 72 + c8 * 8]) =
            *(const half8*)(V + ((size_t)bh * SEQ + z0 + row) * HD + c8 * 8);
    }
    __syncthreads();
    #pragma unroll
    for (int it = 0; it < 4; ++it) {
        int idx = tid + (it << 8);
        int d = idx >> 4, c4 = idx & 15;
        unsigned short a = T[(c4 * 4 + 0) * 72 + d];
        unsigned short b = T[(c4 * 4 + 1) * 72 + d];
        unsigned short c = T[(c4 * 4 + 2) * 72 + d];
        unsigned short e = T[(c4 * 4 + 3) * 72 + d];
        uint2 o = make_uint2((unsigned)a | ((unsigned)b << 16),
                             (unsigned)c | ((unsigned)e << 16));
        *(uint2*)(Vt + ((size_t)bh * HD + d) * SEQ + z0 + (c4 << 2)) = o;
    }
}

// ---------------------------------------------------------------------------
// Flash attention, TRANSPOSED-S formulation.
// S^T = K·Q^T via mfma(A=K-frag, B=Q-frag): C-layout (row=z=4q+r, col=s=l)
// -> softmax state is scalar-per-lane (s=l); P^T in C-layout IS the B-operand
// layout of mfma_f32_16x16x16_f16 (k=4q+j, n=l), so PV (O^T = V^T·P^T) runs
// straight from registers -- no P LDS round-trip.
// Row 0 masked to 0.0f (uniform softmax as ref); other masked = -1e12f.
// ---------------------------------------------------------------------------
__global__ __launch_bounds__(256) void attn_kernel(
    const unsigned short* __restrict__ Qg, const unsigned short* __restrict__ Kg,
    const unsigned short* __restrict__ Vtg, unsigned short* __restrict__ Og)
{
    __shared__ unsigned short Kl[64 * LK];   // K tile [z][d]
    __shared__ unsigned short Vl[64 * LK];   // Vt tile [d][z]

    const int tid  = threadIdx.x;
    const int w    = tid >> 6;
    const int lane = tid & 63;
    const int q    = lane >> 4;
    const int l    = lane & 15;

    const int bid = blockIdx.x;
    const int bh  = bid & (BH - 1);
    const int t_o = bid >> 5;                      // heavy tiles first
    const int st  = (t_o == 0) ? 0 : (32 - t_o);
    const int s0  = st << 6;

    const unsigned short* Qb  = Qg  + (size_t)bh * SEQ * HD;
    const unsigned short* Kb  = Kg  + (size_t)bh * SEQ * HD;
    const unsigned short* Vtb = Vtg + (size_t)bh * HD * SEQ;

    const int s_col = s0 + 16 * w + l;   // this lane's softmax row (S^T col)

    // Q as B-operand: B[k=8q+j][n=l] = Q[s=s_col][d=8q+j] (+32 for k-step 2)
    half8 qB[2];
    {
        const unsigned short* qp = Qb + (size_t)s_col * HD + 8 * q;
        qB[0] = *(const half8*)(qp);
        qB[1] = *(const half8*)(qp + 32);
    }

    float m_run = -INFINITY, l_run = 0.f;
    floatx4 oacc[4];                       // O^T: row d=16nd+4q+r, col s=l
    #pragma unroll
    for (int nd = 0; nd < 4; ++nd) oacc[nd] = (floatx4){0.f, 0.f, 0.f, 0.f};

    const int ntiles = (st == 0) ? (SEQ >> 6) : (st + 1);

    for (int zt = 0; zt < ntiles; ++zt) {
        const int z0 = zt << 6;
        __syncthreads();
        #pragma unroll
        for (int it = 0; it < 2; ++it) {
            int idx = tid + (it << 8);
            int row = idx >> 3, c8 = idx & 7;
            *(half8*)(&Kl[row * LK + c8 * 8]) =
                *(const half8*)(Kb + (size_t)(z0 + row) * HD + c8 * 8);
            *(half8*)(&Vl[row * LK + c8 * 8]) =
                *(const half8*)(Vtb + (size_t)row * SEQ + z0 + c8 * 8);
        }
        __syncthreads();

        // S^T = K Q^T : subtile t covers z in [z0+16t, z0+16t+16)
        floatx4 sacc[4];
        #pragma unroll
        for (int t = 0; t < 4; ++t) {
            sacc[t] = (floatx4){0.f, 0.f, 0.f, 0.f};
            half8 aK0 = *(const half8*)(&Kl[(16 * t + l) * LK + 8 * q]);
            half8 aK1 = *(const half8*)(&Kl[(16 * t + l) * LK + 8 * q + 32]);
            sacc[t] = __builtin_amdgcn_mfma_f32_16x16x32_f16(aK0, qB[0], sacc[t], 0, 0, 0);
            sacc[t] = __builtin_amdgcn_mfma_f32_16x16x32_f16(aK1, qB[1], sacc[t], 0, 0, 0);
        }

        // mask z >= s (diag tile, or everywhere for the st==0 block)
        if (st == 0 || zt == st) {
            float mval = (s_col == 0) ? 0.0f : -1e12f;
            #pragma unroll
            for (int t = 0; t < 4; ++t) {
                #pragma unroll
                for (int r = 0; r < 4; ++r) {
                    int z = z0 + 16 * t + 4 * q + r;
                    if (z >= s_col) sacc[t][r] = mval;
                }
            }
        }

        // scalar-per-lane online softmax (cross-quad combine: xor 16, 32)
        float rm = -INFINITY;
        #pragma unroll
        for (int t = 0; t < 4; ++t)
            #pragma unroll
            for (int r = 0; r < 4; ++r)
                rm = fmaxf(rm, sacc[t][r]);
        rm = fmaxf(rm, __shfl_xor(rm, 16, 64));
        rm = fmaxf(rm, __shfl_xor(rm, 32, 64));
        float mn = fmaxf(m_run, rm);

        float rs = 0.f;
        half4 pB[4];                       // P^T chunk t: B-frag of 16x16x16
        #pragma unroll
        for (int t = 0; t < 4; ++t)
            #pragma unroll
            for (int r = 0; r < 4; ++r) {
                float pf = EXP2(sacc[t][r] - mn);
                rs += pf;
                pB[t][r] = (_Float16)pf;
            }
        rs += __shfl_xor(rs, 16, 64);
        rs += __shfl_xor(rs, 32, 64);

        float alpha = EXP2(m_run - mn);
        l_run = alpha * l_run + rs;
        m_run = mn;
        #pragma unroll
        for (int nd = 0; nd < 4; ++nd) oacc[nd] *= alpha;

        // O^T += V^T P^T : A-frag from Vt LDS (row d=16nd+l, k=z=16t+4q+j)
        #pragma unroll
        for (int t = 0; t < 4; ++t)
            #pragma unroll
            for (int nd = 0; nd < 4; ++nd) {
                half4 vA = *(const half4*)(&Vl[(16 * nd + l) * LK + 16 * t + 4 * q]);
                oacc[nd] = __builtin_amdgcn_mfma_f32_16x16x16f16(vA, pB[t], oacc[nd], 0, 0, 0);
            }
    }

    // epilogue: O[s][d] = O^T/l_run -> f16 [B*S][F]; 4x 8B packed stores
    const int b = bh >> 4, h = bh & 15;
    float inv = 1.0f / l_run;
    unsigned short* op = Og + ((size_t)b * SEQ + s_col) * FDIM + h * HD;
    #pragma unroll
    for (int nd = 0; nd < 4; ++nd) {
        uint2 o = make_uint2(pk_f16(oacc[nd][0] * inv, oacc[nd][1] * inv),
                             pk_f16(oacc[nd][2] * inv, oacc[nd][3] * inv));
        *(uint2*)(op + 16 * nd + 4 * q) = o;
    }
}

// ---------------------------------------------------------------------------
extern "C" void kernel_launch(void* const* d_in, const int* in_sizes, int n_in,
                              void* d_out, int out_size, void* d_ws, size_t ws_size,
                              hipStream_t stream) {
    const float* attend_from = (const float*)d_in[0];
    const float* attend_to   = (const float*)d_in[1];
    const float* w_q   = (const float*)d_in[2];
    const float* b_q   = (const float*)d_in[3];
    const float* w_kv  = (const float*)d_in[4];
    const float* b_kv  = (const float*)d_in[5];
    const float* w_out = (const float*)d_in[6];
    const float* b_out = (const float*)d_in[7];
    float* out = (float*)d_out;

    unsigned short* ws = (unsigned short*)d_ws;
    const size_t E = (size_t)(SB * SEQ) * FDIM;   // 4M elems
    unsigned short* Af   = ws;
    unsigned short* At   = ws + E;
    unsigned short* Qb   = ws + 2 * E;
    unsigned short* Kb   = ws + 3 * E;
    unsigned short* Vb   = ws + 4 * E;
    unsigned short* Vt   = ws + 5 * E;
    unsigned short* Ob   = Vb;                    // reuse V after transpose
    unsigned short* Wqt  = ws + 6 * E;
    unsigned short* Wkvt = ws + 6 * E + E / 4;
    unsigned short* Wot  = ws + 6 * E + E / 4 + E / 2;

    dim3 blk(256);
    const int M = SB * SEQ;   // 4096

    cvt_all<<<dim3(5120), blk, 0, stream>>>(
        attend_from, attend_to, Af, At, w_q, w_kv, w_out, Wqt, Wkvt, Wot);
    gemm_qkv<<<dim3(24, M / 128), blk, 0, stream>>>(
        Af, At, Wqt, Wkvt, b_q, b_kv, Qb, Kb, Vb);
    transpose_v<<<dim3(BH * (SEQ / 64)), blk, 0, stream>>>(Vb, Vt);
    attn_kernel<<<dim3(BH * (SEQ / 64)), blk, 0, stream>>>(Qb, Kb, Vt, Ob);
    gemm_out<<<dim3(FDIM / 128, M / 64), blk, 0, stream>>>(Ob, Wot, b_out, out);
}

// Round 8
// 232.041 us; speedup vs baseline: 1.0276x; 1.0125x over previous
//
#include <hip/hip_runtime.h>
#include <math.h>

#define SB   2
#define SEQ  2048
#define FDIM 1024
#define NH   16
#define HD   64
#define BH   (SB * NH)   // 32
#define LK   72          // attention LDS row stride in f16 elems (64 + 8 pad)

typedef _Float16 half8 __attribute__((ext_vector_type(8)));
typedef _Float16 half4 __attribute__((ext_vector_type(4)));
typedef __attribute__((ext_vector_type(4))) float floatx4;

#if __has_builtin(__builtin_amdgcn_exp2f)
#define EXP2(x) __builtin_amdgcn_exp2f(x)
#else
#define EXP2(x) __expf(0.6931471805599453f * (x))
#endif

__device__ __forceinline__ unsigned pk_f16(float a, float b) {
    unsigned short ha = __builtin_bit_cast(unsigned short, (_Float16)a);
    unsigned short hb = __builtin_bit_cast(unsigned short, (_Float16)b);
    return (unsigned)ha | ((unsigned)hb << 16);
}
__device__ __forceinline__ unsigned short f16_1(float a) {
    _Float16 h = (_Float16)a;
    return __builtin_bit_cast(unsigned short, h);
}
__device__ __forceinline__ void load16_lds(const unsigned short* g, unsigned short* l) {
    __builtin_amdgcn_global_load_lds(
        (const __attribute__((address_space(1))) unsigned int*)g,
        (__attribute__((address_space(3))) unsigned int*)l, 16, 0, 0);
}

// ---------------------------------------------------------------------------
// Fused conversions: blocks [0,4096) activations fp32->f16;
// blocks [4096,5120) weight transpose+convert W[K][N]fp32 -> Wt[N][K]f16.
// ---------------------------------------------------------------------------
__global__ __launch_bounds__(256) void cvt_all(
    const float* __restrict__ in0, const float* __restrict__ in1,
    unsigned short* __restrict__ out0, unsigned short* __restrict__ out1,
    const float* __restrict__ Wq, const float* __restrict__ Wkv,
    const float* __restrict__ Wo, unsigned short* __restrict__ Wqt,
    unsigned short* __restrict__ Wkvt, unsigned short* __restrict__ Wot)
{
    const int tid = threadIdx.x;
    int bx = blockIdx.x;
    if (bx < 4096) {
        const float* in = (bx < 2048) ? in0 : in1;
        unsigned short* out = (bx < 2048) ? out0 : out1;
        int i = ((bx & 2047) * 256 + tid) * 8;
        float4 a = *(const float4*)(in + i);
        float4 b = *(const float4*)(in + i + 4);
        uint4 o;
        o.x = pk_f16(a.x, a.y); o.y = pk_f16(a.z, a.w);
        o.z = pk_f16(b.x, b.y); o.w = pk_f16(b.z, b.w);
        *(uint4*)(out + i) = o;
        return;
    }
    __shared__ float T[64 * 65];
    int id = bx - 4096;
    const float* W; unsigned short* Wt; int N, n0, k0;
    if (id < 256)      { W = Wq;  Wt = Wqt;  N = 1024; n0 = (id & 15) << 6; k0 = (id >> 4) << 6; }
    else if (id < 768) { id -= 256; W = Wkv; Wt = Wkvt; N = 2048; n0 = (id & 31) << 6; k0 = (id >> 5) << 6; }
    else               { id -= 768; W = Wo;  Wt = Wot;  N = 1024; n0 = (id & 15) << 6; k0 = (id >> 4) << 6; }

    #pragma unroll
    for (int i = 0; i < 4; ++i) {
        int idx = tid + (i << 8);
        int row = idx >> 4, c4 = idx & 15;
        float4 v = *(const float4*)(W + (size_t)(k0 + row) * N + n0 + (c4 << 2));
        float* tp = &T[row * 65 + (c4 << 2)];
        tp[0] = v.x; tp[1] = v.y; tp[2] = v.z; tp[3] = v.w;
    }
    __syncthreads();
    #pragma unroll
    for (int i = 0; i < 4; ++i) {
        int idx = tid + (i << 8);
        int n = idx >> 4, c4 = idx & 15;
        float x = T[(c4 * 4 + 0) * 65 + n];
        float y = T[(c4 * 4 + 1) * 65 + n];
        float z = T[(c4 * 4 + 2) * 65 + n];
        float w = T[(c4 * 4 + 3) * 65 + n];
        uint2 o = make_uint2(pk_f16(x, y), pk_f16(z, w));
        *(uint2*)(Wt + (size_t)(n0 + n) * FDIM + k0 + (c4 << 2)) = o;
    }
}

// ---------------------------------------------------------------------------
// f16 MFMA GEMM core (m97 structure): acc = A @ Wt^T, 128x128 tile, BK=32.
// ---------------------------------------------------------------------------
__device__ __forceinline__ void gemm_core(
    const unsigned short* __restrict__ A, const unsigned short* __restrict__ Wt,
    int m0, int n0, int K, floatx4 (&acc)[4][4],
    unsigned short* Al, unsigned short* Bl)
{
    const int tid  = threadIdx.x;
    const int w    = tid >> 6;
    const int lane = tid & 63;
    const int q    = lane >> 4, l = lane & 15;
    const int wm = (w >> 1) * 64, wn = (w & 1) * 64;

    for (int k0 = 0; k0 < K; k0 += 32) {
        __syncthreads();
        #pragma unroll
        for (int it = 0; it < 2; ++it) {
            int c = (w * 2 + it) * 64 + lane;
            int row = c >> 2, o = (c & 3) * 8;
            load16_lds(A  + (size_t)(m0 + row) * K + k0 + o, Al + c * 8);
            load16_lds(Wt + (size_t)(n0 + row) * K + k0 + o, Bl + c * 8);
        }
        __syncthreads();

        half8 aF[4], bF[4];
        #pragma unroll
        for (int i = 0; i < 4; ++i)
            aF[i] = *(const half8*)(Al + (wm + 16 * i + l) * 32 + 8 * q);
        #pragma unroll
        for (int j = 0; j < 4; ++j)
            bF[j] = *(const half8*)(Bl + (wn + 16 * j + l) * 32 + 8 * q);
        #pragma unroll
        for (int i = 0; i < 4; ++i)
            #pragma unroll
            for (int j = 0; j < 4; ++j)
                acc[i][j] = __builtin_amdgcn_mfma_f32_16x16x32_f16(
                    aF[i], bF[j], acc[i][j], 0, 0, 0);
    }
}

// ---------------------------------------------------------------------------
// Merged Q + KV projection GEMM. grid (24, 32): bx<8 -> Q, else KV.
// Q output is PRE-SCALED by log2(e) so attention can use exp2 directly.
// ---------------------------------------------------------------------------
__global__ __launch_bounds__(256) void gemm_qkv(
    const unsigned short* __restrict__ Af, const unsigned short* __restrict__ At,
    const unsigned short* __restrict__ Wqt, const unsigned short* __restrict__ Wkvt,
    const float* __restrict__ bq, const float* __restrict__ bkv,
    unsigned short* __restrict__ Qo, unsigned short* __restrict__ Ko,
    unsigned short* __restrict__ Vo)
{
    __shared__ unsigned short Al[128 * 32];
    __shared__ unsigned short Bl[128 * 32];

    const int tid  = threadIdx.x;
    const int w    = tid >> 6;
    const int lane = tid & 63;
    const int q    = lane >> 4, l = lane & 15;
    const int wm = (w >> 1) * 64, wn = (w & 1) * 64;
    const int m0 = blockIdx.y * 128;

    bool isQ = blockIdx.x < 8;
    const unsigned short* A  = isQ ? Af : At;
    const unsigned short* Wt = isQ ? Wqt : Wkvt;
    const float* bias        = isQ ? bq : bkv;
    const int n0 = (isQ ? blockIdx.x : (blockIdx.x - 8)) * 128;

    floatx4 acc[4][4];
    #pragma unroll
    for (int i = 0; i < 4; ++i)
        #pragma unroll
        for (int j = 0; j < 4; ++j)
            acc[i][j] = (floatx4){0.f, 0.f, 0.f, 0.f};

    gemm_core(A, Wt, m0, n0, FDIM, acc, Al, Bl);

    float bj[4];
    #pragma unroll
    for (int j = 0; j < 4; ++j) bj[j] = bias[n0 + wn + 16 * j + l];

    const float qscale = isQ ? 1.4426950408889634f : 1.0f;

    #pragma unroll
    for (int i = 0; i < 4; ++i)
        #pragma unroll
        for (int j = 0; j < 4; ++j) {
            int n = n0 + wn + 16 * j + l;
            #pragma unroll
            for (int r = 0; r < 4; ++r) {
                int m = m0 + wm + 16 * i + 4 * q + r;
                float v = (acc[i][j][r] + bj[j]) * qscale;
                int b = m >> 11, s = m & (SEQ - 1);
                if (isQ) {
                    int h = n >> 6, dd = n & 63;
                    Qo[((size_t)(b * NH + h) * SEQ + s) * HD + dd] = f16_1(v);
                } else {
                    int np = (n < FDIM) ? n : (n - FDIM);
                    unsigned short* Cd = (n < FDIM) ? Ko : Vo;
                    int h = np >> 6, dd = np & 63;
                    Cd[((size_t)(b * NH + h) * SEQ + s) * HD + dd] = f16_1(v);
                }
            }
        }
}

// ---------------------------------------------------------------------------
// Out-projection GEMM: 64x128 tile, 512 blocks (2/CU hides barrier drain).
// ---------------------------------------------------------------------------
__global__ __launch_bounds__(256) void gemm_out(
    const unsigned short* __restrict__ A, const unsigned short* __restrict__ Wt,
    const float* __restrict__ bias, float* __restrict__ C)
{
    __shared__ unsigned short Al[64 * 32];    // 4 KB
    __shared__ unsigned short Bl[128 * 32];   // 8 KB

    const int tid  = threadIdx.x;
    const int w    = tid >> 6;
    const int lane = tid & 63;
    const int q    = lane >> 4, l = lane & 15;
    const int m0 = blockIdx.y * 64, n0 = blockIdx.x * 128;
    const int wn = 32 * w;

    floatx4 acc[4][2];
    #pragma unroll
    for (int i = 0; i < 4; ++i)
        #pragma unroll
        for (int j = 0; j < 2; ++j)
            acc[i][j] = (floatx4){0.f, 0.f, 0.f, 0.f};

    for (int k0 = 0; k0 < FDIM; k0 += 32) {
        __syncthreads();
        {
            int row = tid >> 2, o = (tid & 3) * 8;
            load16_lds(A + (size_t)(m0 + row) * FDIM + k0 + o, Al + tid * 8);
        }
        #pragma unroll
        for (int it = 0; it < 2; ++it) {
            int c = tid + (it << 8);
            int row = c >> 2, o = (c & 3) * 8;
            load16_lds(Wt + (size_t)(n0 + row) * FDIM + k0 + o, Bl + c * 8);
        }
        __syncthreads();

        half8 aF[4], bF[2];
        #pragma unroll
        for (int i = 0; i < 4; ++i)
            aF[i] = *(const half8*)(Al + (16 * i + l) * 32 + 8 * q);
        #pragma unroll
        for (int j = 0; j < 2; ++j)
            bF[j] = *(const half8*)(Bl + (wn + 16 * j + l) * 32 + 8 * q);
        #pragma unroll
        for (int i = 0; i < 4; ++i)
            #pragma unroll
            for (int j = 0; j < 2; ++j)
                acc[i][j] = __builtin_amdgcn_mfma_f32_16x16x32_f16(
                    aF[i], bF[j], acc[i][j], 0, 0, 0);
    }

    float bj[2];
    #pragma unroll
    for (int j = 0; j < 2; ++j) bj[j] = bias[n0 + wn + 16 * j + l];

    #pragma unroll
    for (int i = 0; i < 4; ++i)
        #pragma unroll
        for (int j = 0; j < 2; ++j) {
            int n = n0 + wn + 16 * j + l;
            #pragma unroll
            for (int r = 0; r < 4; ++r) {
                int m = m0 + 16 * i + 4 * q + r;
                C[(size_t)m * FDIM + n] = acc[i][j][r] + bj[j];
            }
        }
}

// ---------------------------------------------------------------------------
// blocks [0,1024): V [bh][z][d] f16 -> Vt [bh][d][z] f16
// blocks [1024,1056): Vsum[bh][d] = sum_z V[bh][z][d] (fp32) for row-0 patch
// ---------------------------------------------------------------------------
__global__ __launch_bounds__(256) void transpose_v(
    const unsigned short* __restrict__ V, unsigned short* __restrict__ Vt,
    float* __restrict__ Vsum)
{
    __shared__ unsigned short T[64 * 72];
    __shared__ float Sm[32][64];
    const int tid = threadIdx.x;
    const int bx = blockIdx.x;

    if (bx >= 1024) {
        const int bh = bx - 1024;
        const int dg = tid & 7, stripe = tid >> 3;   // 32 stripes x 64 z
        const unsigned short* Vp =
            V + ((size_t)bh * SEQ + stripe * 64) * HD + dg * 8;
        float s[8] = {0.f, 0.f, 0.f, 0.f, 0.f, 0.f, 0.f, 0.f};
        for (int i = 0; i < 64; ++i) {
            half8 v = *(const half8*)(Vp + (size_t)i * HD);
            #pragma unroll
            for (int j = 0; j < 8; ++j) s[j] += (float)v[j];
        }
        #pragma unroll
        for (int j = 0; j < 8; ++j) Sm[stripe][dg * 8 + j] = s[j];
        __syncthreads();
        if (tid < 64) {
            float acc = 0.f;
            #pragma unroll
            for (int st2 = 0; st2 < 32; ++st2) acc += Sm[st2][tid];
            Vsum[bh * 64 + tid] = acc;
        }
        return;
    }

    const int zt = bx & 31, bh = bx >> 5;
    const int z0 = zt << 6;
    #pragma unroll
    for (int it = 0; it < 2; ++it) {
        int idx = tid + (it << 8);
        int row = idx >> 3, c8 = idx & 7;
        *(half8*)(&T[row * 72 + c8 * 8]) =
            *(const half8*)(V + ((size_t)bh * SEQ + z0 + row) * HD + c8 * 8);
    }
    __syncthreads();
    #pragma unroll
    for (int it = 0; it < 4; ++it) {
        int idx = tid + (it << 8);
        int d = idx >> 4, c4 = idx & 15;
        unsigned short a = T[(c4 * 4 + 0) * 72 + d];
        unsigned short b = T[(c4 * 4 + 1) * 72 + d];
        unsigned short c = T[(c4 * 4 + 2) * 72 + d];
        unsigned short e = T[(c4 * 4 + 3) * 72 + d];
        uint2 o = make_uint2((unsigned)a | ((unsigned)b << 16),
                             (unsigned)c | ((unsigned)e << 16));
        *(uint2*)(Vt + ((size_t)bh * HD + d) * SEQ + z0 + (c4 << 2)) = o;
    }
}

// ---------------------------------------------------------------------------
// Flash attention, transposed-S, PAIRED s-tiles sharing staged K/V.
// Block = (bh, pair p): group A = s-tile 31-p, group B = s-tile p.
// Every pair costs (32-p)+(p+1) = 33 group-tiles -> uniform block duration.
// K A-frags and V A-frags are read from LDS ONCE and feed both groups.
// Row 0 (all-masked, uniform softmax) is patched analytically from Vsum.
// ---------------------------------------------------------------------------
__global__ __launch_bounds__(256) void attn_kernel(
    const unsigned short* __restrict__ Qg, const unsigned short* __restrict__ Kg,
    const unsigned short* __restrict__ Vtg, const float* __restrict__ Vsum,
    unsigned short* __restrict__ Og)
{
    __shared__ unsigned short Kl[64 * LK];   // K tile [z][d]
    __shared__ unsigned short Vl[64 * LK];   // Vt tile [d][z]

    const int tid  = threadIdx.x;
    const int w    = tid >> 6;
    const int lane = tid & 63;
    const int q    = lane >> 4;
    const int l    = lane & 15;

    const int bid = blockIdx.x;
    const int bh  = bid & (BH - 1);
    const int p   = bid >> 5;              // 0..15, heavy (p=0) dispatched first
    const int stA = 31 - p;                // heavy s-tile, needs stA+1 z-tiles
    const int stB = p;                     // light s-tile
    const int ntB = p + 1;                 // tiles for B (p=0: rows 1..63 need
                                           // only tile 0; row 0 patched)
    const int sweep = stA + 1;             // z-tiles staged by this block

    const unsigned short* Qb  = Qg  + (size_t)bh * SEQ * HD;
    const unsigned short* Kb  = Kg  + (size_t)bh * SEQ * HD;
    const unsigned short* Vtb = Vtg + (size_t)bh * HD * SEQ;

    const int s_colA = (stA << 6) + 16 * w + l;
    const int s_colB = (stB << 6) + 16 * w + l;

    half8 qBA[2], qBB[2];
    {
        const unsigned short* qp = Qb + (size_t)s_colA * HD + 8 * q;
        qBA[0] = *(const half8*)(qp);
        qBA[1] = *(const half8*)(qp + 32);
        qp = Qb + (size_t)s_colB * HD + 8 * q;
        qBB[0] = *(const half8*)(qp);
        qBB[1] = *(const half8*)(qp + 32);
    }

    float m_runA = -INFINITY, l_runA = 0.f;
    float m_runB = -INFINITY, l_runB = 0.f;
    floatx4 oaccA[4], oaccB[4];
    #pragma unroll
    for (int nd = 0; nd < 4; ++nd) {
        oaccA[nd] = (floatx4){0.f, 0.f, 0.f, 0.f};
        oaccB[nd] = (floatx4){0.f, 0.f, 0.f, 0.f};
    }

    for (int zt = 0; zt < sweep; ++zt) {
        const int z0 = zt << 6;
        __syncthreads();
        #pragma unroll
        for (int it = 0; it < 2; ++it) {
            int idx = tid + (it << 8);
            int row = idx >> 3, c8 = idx & 7;
            *(half8*)(&Kl[row * LK + c8 * 8]) =
                *(const half8*)(Kb + (size_t)(z0 + row) * HD + c8 * 8);
            *(half8*)(&Vl[row * LK + c8 * 8]) =
                *(const half8*)(Vtb + (size_t)row * SEQ + z0 + c8 * 8);
        }
        __syncthreads();

        const bool bact = (zt < ntB);

        // S^T for both groups from SHARED K A-frags
        floatx4 saccA[4], saccB[4];
        #pragma unroll
        for (int t = 0; t < 4; ++t) {
            saccA[t] = (floatx4){0.f, 0.f, 0.f, 0.f};
            saccB[t] = (floatx4){0.f, 0.f, 0.f, 0.f};
            half8 aK0 = *(const half8*)(&Kl[(16 * t + l) * LK + 8 * q]);
            half8 aK1 = *(const half8*)(&Kl[(16 * t + l) * LK + 8 * q + 32]);
            saccA[t] = __builtin_amdgcn_mfma_f32_16x16x32_f16(aK0, qBA[0], saccA[t], 0, 0, 0);
            saccA[t] = __builtin_amdgcn_mfma_f32_16x16x32_f16(aK1, qBA[1], saccA[t], 0, 0, 0);
            if (bact) {
                saccB[t] = __builtin_amdgcn_mfma_f32_16x16x32_f16(aK0, qBB[0], saccB[t], 0, 0, 0);
                saccB[t] = __builtin_amdgcn_mfma_f32_16x16x32_f16(aK1, qBB[1], saccB[t], 0, 0, 0);
            }
        }

        // masks (diag tiles only; group A never contains row 0)
        if (zt == stA) {
            #pragma unroll
            for (int t = 0; t < 4; ++t)
                #pragma unroll
                for (int r = 0; r < 4; ++r) {
                    int z = z0 + 16 * t + 4 * q + r;
                    if (z >= s_colA) saccA[t][r] = -1e12f;
                }
        }
        if (bact && zt == stB) {
            float mval = (s_colB == 0) ? 0.0f : -1e12f;
            #pragma unroll
            for (int t = 0; t < 4; ++t)
                #pragma unroll
                for (int r = 0; r < 4; ++r) {
                    int z = z0 + 16 * t + 4 * q + r;
                    if (z >= s_colB) saccB[t][r] = mval;
                }
        }

        // online softmax, scalar-per-lane (cross-quad: xor 16, 32)
        half4 pBA[4], pBB[4];
        {
            float rm = -INFINITY;
            #pragma unroll
            for (int t = 0; t < 4; ++t)
                #pragma unroll
                for (int r = 0; r < 4; ++r) rm = fmaxf(rm, saccA[t][r]);
            rm = fmaxf(rm, __shfl_xor(rm, 16, 64));
            rm = fmaxf(rm, __shfl_xor(rm, 32, 64));
            float mn = fmaxf(m_runA, rm);
            float rs = 0.f;
            #pragma unroll
            for (int t = 0; t < 4; ++t)
                #pragma unroll
                for (int r = 0; r < 4; ++r) {
                    float pf = EXP2(saccA[t][r] - mn);
                    rs += pf;
                    pBA[t][r] = (_Float16)pf;
                }
            rs += __shfl_xor(rs, 16, 64);
            rs += __shfl_xor(rs, 32, 64);
            float alpha = EXP2(m_runA - mn);
            l_runA = alpha * l_runA + rs;
            m_runA = mn;
            #pragma unroll
            for (int nd = 0; nd < 4; ++nd) oaccA[nd] *= alpha;
        }
        if (bact) {
            float rm = -INFINITY;
            #pragma unroll
            for (int t = 0; t < 4; ++t)
                #pragma unroll
                for (int r = 0; r < 4; ++r) rm = fmaxf(rm, saccB[t][r]);
            rm = fmaxf(rm, __shfl_xor(rm, 16, 64));
            rm = fmaxf(rm, __shfl_xor(rm, 32, 64));
            float mn = fmaxf(m_runB, rm);
            float rs = 0.f;
            #pragma unroll
            for (int t = 0; t < 4; ++t)
                #pragma unroll
                for (int r = 0; r < 4; ++r) {
                    float pf = EXP2(saccB[t][r] - mn);
                    rs += pf;
                    pBB[t][r] = (_Float16)pf;
                }
            rs += __shfl_xor(rs, 16, 64);
            rs += __shfl_xor(rs, 32, 64);
            float alpha = EXP2(m_runB - mn);
            l_runB = alpha * l_runB + rs;
            m_runB = mn;
            #pragma unroll
            for (int nd = 0; nd < 4; ++nd) oaccB[nd] *= alpha;
        }

        // O^T += V^T P^T : V A-frags read ONCE, feed both groups
        #pragma unroll
        for (int t = 0; t < 4; ++t)
            #pragma unroll
            for (int nd = 0; nd < 4; ++nd) {
                half4 vA = *(const half4*)(&Vl[(16 * nd + l) * LK + 16 * t + 4 * q]);
                oaccA[nd] = __builtin_amdgcn_mfma_f32_16x16x16f16(vA, pBA[t], oaccA[nd], 0, 0, 0);
                if (bact)
                    oaccB[nd] = __builtin_amdgcn_mfma_f32_16x16x16f16(vA, pBB[t], oaccB[nd], 0, 0, 0);
            }
    }

    // epilogue
    const int b = bh >> 4, h = bh & 15;
    {
        float inv = 1.0f / l_runA;
        unsigned short* op = Og + ((size_t)b * SEQ + s_colA) * FDIM + h * HD;
        #pragma unroll
        for (int nd = 0; nd < 4; ++nd) {
            uint2 o = make_uint2(pk_f16(oaccA[nd][0] * inv, oaccA[nd][1] * inv),
                                 pk_f16(oaccA[nd][2] * inv, oaccA[nd][3] * inv));
            *(uint2*)(op + 16 * nd + 4 * q) = o;
        }
    }
    {
        float inv = 1.0f / l_runB;
        if (s_colB == 0) {                 // row 0: O = mean(V), analytically
            inv = 1.0f / 2048.0f;
            #pragma unroll
            for (int nd = 0; nd < 4; ++nd) {
                float4 vs = *(const float4*)(Vsum + bh * 64 + 16 * nd + 4 * q);
                oaccB[nd] = (floatx4){vs.x, vs.y, vs.z, vs.w};
            }
        }
        unsigned short* op = Og + ((size_t)b * SEQ + s_colB) * FDIM + h * HD;
        #pragma unroll
        for (int nd = 0; nd < 4; ++nd) {
            uint2 o = make_uint2(pk_f16(oaccB[nd][0] * inv, oaccB[nd][1] * inv),
                                 pk_f16(oaccB[nd][2] * inv, oaccB[nd][3] * inv));
            *(uint2*)(op + 16 * nd + 4 * q) = o;
        }
    }
}

// ---------------------------------------------------------------------------
extern "C" void kernel_launch(void* const* d_in, const int* in_sizes, int n_in,
                              void* d_out, int out_size, void* d_ws, size_t ws_size,
                              hipStream_t stream) {
    const float* attend_from = (const float*)d_in[0];
    const float* attend_to   = (const float*)d_in[1];
    const float* w_q   = (const float*)d_in[2];
    const float* b_q   = (const float*)d_in[3];
    const float* w_kv  = (const float*)d_in[4];
    const float* b_kv  = (const float*)d_in[5];
    const float* w_out = (const float*)d_in[6];
    const float* b_out = (const float*)d_in[7];
    float* out = (float*)d_out;

    unsigned short* ws = (unsigned short*)d_ws;
    const size_t E = (size_t)(SB * SEQ) * FDIM;   // 4M elems
    unsigned short* Af   = ws;
    unsigned short* At   = ws + E;
    unsigned short* Qb   = ws + 2 * E;
    unsigned short* Kb   = ws + 3 * E;
    unsigned short* Vb   = ws + 4 * E;
    unsigned short* Vt   = ws + 5 * E;
    unsigned short* Ob   = Vb;                    // reuse V after transpose
    unsigned short* Wqt  = ws + 6 * E;
    unsigned short* Wkvt = ws + 6 * E + E / 4;
    unsigned short* Wot  = ws + 6 * E + E / 4 + E / 2;
    float*          Vsum = (float*)(ws + 7 * E);  // 2048 fp32

    dim3 blk(256);
    const int M = SB * SEQ;   // 4096

    cvt_all<<<dim3(5120), blk, 0, stream>>>(
        attend_from, attend_to, Af, At, w_q, w_kv, w_out, Wqt, Wkvt, Wot);
    gemm_qkv<<<dim3(24, M / 128), blk, 0, stream>>>(
        Af, At, Wqt, Wkvt, b_q, b_kv, Qb, Kb, Vb);
    transpose_v<<<dim3(1024 + BH), blk, 0, stream>>>(Vb, Vt, Vsum);
    attn_kernel<<<dim3(BH * 16), blk, 0, stream>>>(Qb, Kb, Vt, Vsum, Ob);
    gemm_out<<<dim3(FDIM / 128, M / 64), blk, 0, stream>>>(Ob, Wot, b_out, out);
}

// Round 10
// 229.013 us; speedup vs baseline: 1.0412x; 1.0132x over previous
//
#include <hip/hip_runtime.h>
#include <math.h>

#define SB   2
#define SEQ  2048
#define FDIM 1024
#define NH   16
#define HD   64
#define BH   (SB * NH)   // 32
#define LK   72          // attention LDS row stride in f16 elems (64 + 8 pad)

typedef _Float16 half8 __attribute__((ext_vector_type(8)));
typedef _Float16 half4 __attribute__((ext_vector_type(4)));
typedef _Float16 half2t __attribute__((ext_vector_type(2)));
typedef __attribute__((ext_vector_type(4))) float floatx4;

#if __has_builtin(__builtin_amdgcn_exp2f)
#define EXP2(x) __builtin_amdgcn_exp2f(x)
#else
#define EXP2(x) __expf(0.6931471805599453f * (x))
#endif

// RNE pack (activations/weights/O) — plain casts
__device__ __forceinline__ unsigned pk_f16(float a, float b) {
    unsigned short ha = __builtin_bit_cast(unsigned short, (_Float16)a);
    unsigned short hb = __builtin_bit_cast(unsigned short, (_Float16)b);
    return (unsigned)ha | ((unsigned)hb << 16);
}
__device__ __forceinline__ unsigned short f16_1(float a) {
    _Float16 h = (_Float16)a;
    return __builtin_bit_cast(unsigned short, h);
}
// RTZ packed cvt — used ONLY for P (bias cancels in P/sum(P)).
// NOTE: builtin returns __fp16 ext_vector(2) -> bit_cast to our half2t.
#if __has_builtin(__builtin_amdgcn_cvt_pkrtz)
__device__ __forceinline__ half2t cvt_pk(float a, float b) {
    return __builtin_bit_cast(half2t, __builtin_amdgcn_cvt_pkrtz(a, b));
}
#else
__device__ __forceinline__ half2t cvt_pk(float a, float b) {
    half2t h; h[0] = (_Float16)a; h[1] = (_Float16)b; return h;
}
#endif
__device__ __forceinline__ void load16_lds(const unsigned short* g, unsigned short* l) {
    __builtin_amdgcn_global_load_lds(
        (const __attribute__((address_space(1))) unsigned int*)g,
        (__attribute__((address_space(3))) unsigned int*)l, 16, 0, 0);
}

// ---------------------------------------------------------------------------
// Fused conversions: blocks [0,4096) activations fp32->f16;
// blocks [4096,5120) weight transpose+convert W[K][N]fp32 -> Wt[N][K]f16.
// ---------------------------------------------------------------------------
__global__ __launch_bounds__(256) void cvt_all(
    const float* __restrict__ in0, const float* __restrict__ in1,
    unsigned short* __restrict__ out0, unsigned short* __restrict__ out1,
    const float* __restrict__ Wq, const float* __restrict__ Wkv,
    const float* __restrict__ Wo, unsigned short* __restrict__ Wqt,
    unsigned short* __restrict__ Wkvt, unsigned short* __restrict__ Wot)
{
    const int tid = threadIdx.x;
    int bx = blockIdx.x;
    if (bx < 4096) {
        const float* in = (bx < 2048) ? in0 : in1;
        unsigned short* out = (bx < 2048) ? out0 : out1;
        int i = ((bx & 2047) * 256 + tid) * 8;
        float4 a = *(const float4*)(in + i);
        float4 b = *(const float4*)(in + i + 4);
        uint4 o;
        o.x = pk_f16(a.x, a.y); o.y = pk_f16(a.z, a.w);
        o.z = pk_f16(b.x, b.y); o.w = pk_f16(b.z, b.w);
        *(uint4*)(out + i) = o;
        return;
    }
    __shared__ float T[64 * 65];
    int id = bx - 4096;
    const float* W; unsigned short* Wt; int N, n0, k0;
    if (id < 256)      { W = Wq;  Wt = Wqt;  N = 1024; n0 = (id & 15) << 6; k0 = (id >> 4) << 6; }
    else if (id < 768) { id -= 256; W = Wkv; Wt = Wkvt; N = 2048; n0 = (id & 31) << 6; k0 = (id >> 5) << 6; }
    else               { id -= 768; W = Wo;  Wt = Wot;  N = 1024; n0 = (id & 15) << 6; k0 = (id >> 4) << 6; }

    #pragma unroll
    for (int i = 0; i < 4; ++i) {
        int idx = tid + (i << 8);
        int row = idx >> 4, c4 = idx & 15;
        float4 v = *(const float4*)(W + (size_t)(k0 + row) * N + n0 + (c4 << 2));
        float* tp = &T[row * 65 + (c4 << 2)];
        tp[0] = v.x; tp[1] = v.y; tp[2] = v.z; tp[3] = v.w;
    }
    __syncthreads();
    #pragma unroll
    for (int i = 0; i < 4; ++i) {
        int idx = tid + (i << 8);
        int n = idx >> 4, c4 = idx & 15;
        float x = T[(c4 * 4 + 0) * 65 + n];
        float y = T[(c4 * 4 + 1) * 65 + n];
        float z = T[(c4 * 4 + 2) * 65 + n];
        float w = T[(c4 * 4 + 3) * 65 + n];
        uint2 o = make_uint2(pk_f16(x, y), pk_f16(z, w));
        *(uint2*)(Wt + (size_t)(n0 + n) * FDIM + k0 + (c4 << 2)) = o;
    }
}

// ---------------------------------------------------------------------------
// f16 MFMA GEMM core (m97 structure): acc = A @ Wt^T, 128x128 tile, BK=32.
// ---------------------------------------------------------------------------
__device__ __forceinline__ void gemm_core(
    const unsigned short* __restrict__ A, const unsigned short* __restrict__ Wt,
    int m0, int n0, int K, floatx4 (&acc)[4][4],
    unsigned short* Al, unsigned short* Bl)
{
    const int tid  = threadIdx.x;
    const int w    = tid >> 6;
    const int lane = tid & 63;
    const int q    = lane >> 4, l = lane & 15;
    const int wm = (w >> 1) * 64, wn = (w & 1) * 64;

    for (int k0 = 0; k0 < K; k0 += 32) {
        __syncthreads();
        #pragma unroll
        for (int it = 0; it < 2; ++it) {
            int c = (w * 2 + it) * 64 + lane;
            int row = c >> 2, o = (c & 3) * 8;
            load16_lds(A  + (size_t)(m0 + row) * K + k0 + o, Al + c * 8);
            load16_lds(Wt + (size_t)(n0 + row) * K + k0 + o, Bl + c * 8);
        }
        __syncthreads();

        half8 aF[4], bF[4];
        #pragma unroll
        for (int i = 0; i < 4; ++i)
            aF[i] = *(const half8*)(Al + (wm + 16 * i + l) * 32 + 8 * q);
        #pragma unroll
        for (int j = 0; j < 4; ++j)
            bF[j] = *(const half8*)(Bl + (wn + 16 * j + l) * 32 + 8 * q);
        #pragma unroll
        for (int i = 0; i < 4; ++i)
            #pragma unroll
            for (int j = 0; j < 4; ++j)
                acc[i][j] = __builtin_amdgcn_mfma_f32_16x16x32_f16(
                    aF[i], bF[j], acc[i][j], 0, 0, 0);
    }
}

// ---------------------------------------------------------------------------
// Merged Q + KV projection GEMM. grid (24, 32): bx<8 -> Q, else KV.
// Q output is PRE-SCALED by log2(e) so attention can use exp2 directly.
// ---------------------------------------------------------------------------
__global__ __launch_bounds__(256) void gemm_qkv(
    const unsigned short* __restrict__ Af, const unsigned short* __restrict__ At,
    const unsigned short* __restrict__ Wqt, const unsigned short* __restrict__ Wkvt,
    const float* __restrict__ bq, const float* __restrict__ bkv,
    unsigned short* __restrict__ Qo, unsigned short* __restrict__ Ko,
    unsigned short* __restrict__ Vo)
{
    __shared__ unsigned short Al[128 * 32];
    __shared__ unsigned short Bl[128 * 32];

    const int tid  = threadIdx.x;
    const int w    = tid >> 6;
    const int lane = tid & 63;
    const int q    = lane >> 4, l = lane & 15;
    const int wm = (w >> 1) * 64, wn = (w & 1) * 64;
    const int m0 = blockIdx.y * 128;

    bool isQ = blockIdx.x < 8;
    const unsigned short* A  = isQ ? Af : At;
    const unsigned short* Wt = isQ ? Wqt : Wkvt;
    const float* bias        = isQ ? bq : bkv;
    const int n0 = (isQ ? blockIdx.x : (blockIdx.x - 8)) * 128;

    floatx4 acc[4][4];
    #pragma unroll
    for (int i = 0; i < 4; ++i)
        #pragma unroll
        for (int j = 0; j < 4; ++j)
            acc[i][j] = (floatx4){0.f, 0.f, 0.f, 0.f};

    gemm_core(A, Wt, m0, n0, FDIM, acc, Al, Bl);

    float bj[4];
    #pragma unroll
    for (int j = 0; j < 4; ++j) bj[j] = bias[n0 + wn + 16 * j + l];

    const float qscale = isQ ? 1.4426950408889634f : 1.0f;

    #pragma unroll
    for (int i = 0; i < 4; ++i)
        #pragma unroll
        for (int j = 0; j < 4; ++j) {
            int n = n0 + wn + 16 * j + l;
            #pragma unroll
            for (int r = 0; r < 4; ++r) {
                int m = m0 + wm + 16 * i + 4 * q + r;
                float v = (acc[i][j][r] + bj[j]) * qscale;
                int b = m >> 11, s = m & (SEQ - 1);
                if (isQ) {
                    int h = n >> 6, dd = n & 63;
                    Qo[((size_t)(b * NH + h) * SEQ + s) * HD + dd] = f16_1(v);
                } else {
                    int np = (n < FDIM) ? n : (n - FDIM);
                    unsigned short* Cd = (n < FDIM) ? Ko : Vo;
                    int h = np >> 6, dd = np & 63;
                    Cd[((size_t)(b * NH + h) * SEQ + s) * HD + dd] = f16_1(v);
                }
            }
        }
}

// ---------------------------------------------------------------------------
// Out-projection GEMM: 64x128 tile, 512 blocks (2/CU hides barrier drain).
// ---------------------------------------------------------------------------
__global__ __launch_bounds__(256) void gemm_out(
    const unsigned short* __restrict__ A, const unsigned short* __restrict__ Wt,
    const float* __restrict__ bias, float* __restrict__ C)
{
    __shared__ unsigned short Al[64 * 32];    // 4 KB
    __shared__ unsigned short Bl[128 * 32];   // 8 KB

    const int tid  = threadIdx.x;
    const int w    = tid >> 6;
    const int lane = tid & 63;
    const int q    = lane >> 4, l = lane & 15;
    const int m0 = blockIdx.y * 64, n0 = blockIdx.x * 128;
    const int wn = 32 * w;

    floatx4 acc[4][2];
    #pragma unroll
    for (int i = 0; i < 4; ++i)
        #pragma unroll
        for (int j = 0; j < 2; ++j)
            acc[i][j] = (floatx4){0.f, 0.f, 0.f, 0.f};

    for (int k0 = 0; k0 < FDIM; k0 += 32) {
        __syncthreads();
        {
            int row = tid >> 2, o = (tid & 3) * 8;
            load16_lds(A + (size_t)(m0 + row) * FDIM + k0 + o, Al + tid * 8);
        }
        #pragma unroll
        for (int it = 0; it < 2; ++it) {
            int c = tid + (it << 8);
            int row = c >> 2, o = (c & 3) * 8;
            load16_lds(Wt + (size_t)(n0 + row) * FDIM + k0 + o, Bl + c * 8);
        }
        __syncthreads();

        half8 aF[4], bF[2];
        #pragma unroll
        for (int i = 0; i < 4; ++i)
            aF[i] = *(const half8*)(Al + (16 * i + l) * 32 + 8 * q);
        #pragma unroll
        for (int j = 0; j < 2; ++j)
            bF[j] = *(const half8*)(Bl + (wn + 16 * j + l) * 32 + 8 * q);
        #pragma unroll
        for (int i = 0; i < 4; ++i)
            #pragma unroll
            for (int j = 0; j < 2; ++j)
                acc[i][j] = __builtin_amdgcn_mfma_f32_16x16x32_f16(
                    aF[i], bF[j], acc[i][j], 0, 0, 0);
    }

    float bj[2];
    #pragma unroll
    for (int j = 0; j < 2; ++j) bj[j] = bias[n0 + wn + 16 * j + l];

    #pragma unroll
    for (int i = 0; i < 4; ++i)
        #pragma unroll
        for (int j = 0; j < 2; ++j) {
            int n = n0 + wn + 16 * j + l;
            #pragma unroll
            for (int r = 0; r < 4; ++r) {
                int m = m0 + 16 * i + 4 * q + r;
                C[(size_t)m * FDIM + n] = acc[i][j][r] + bj[j];
            }
        }
}

// ---------------------------------------------------------------------------
// blocks [0,1024): V [bh][z][d] f16 -> Vt [bh][d][z] f16
// blocks [1024,1056): Vsum[bh][d] = sum_z V[bh][z][d] (fp32) for row-0 patch
// ---------------------------------------------------------------------------
__global__ __launch_bounds__(256) void transpose_v(
    const unsigned short* __restrict__ V, unsigned short* __restrict__ Vt,
    float* __restrict__ Vsum)
{
    __shared__ unsigned short T[64 * 72];
    __shared__ float Sm[32][64];
    const int tid = threadIdx.x;
    const int bx = blockIdx.x;

    if (bx >= 1024) {
        const int bh = bx - 1024;
        const int dg = tid & 7, stripe = tid >> 3;   // 32 stripes x 64 z
        const unsigned short* Vp =
            V + ((size_t)bh * SEQ + stripe * 64) * HD + dg * 8;
        float s[8] = {0.f, 0.f, 0.f, 0.f, 0.f, 0.f, 0.f, 0.f};
        for (int i = 0; i < 64; ++i) {
            half8 v = *(const half8*)(Vp + (size_t)i * HD);
            #pragma unroll
            for (int j = 0; j < 8; ++j) s[j] += (float)v[j];
        }
        #pragma unroll
        for (int j = 0; j < 8; ++j) Sm[stripe][dg * 8 + j] = s[j];
        __syncthreads();
        if (tid < 64) {
            float acc = 0.f;
            #pragma unroll
            for (int st2 = 0; st2 < 32; ++st2) acc += Sm[st2][tid];
            Vsum[bh * 64 + tid] = acc;
        }
        return;
    }

    const int zt = bx & 31, bh = bx >> 5;
    const int z0 = zt << 6;
    #pragma unroll
    for (int it = 0; it < 2; ++it) {
        int idx = tid + (it << 8);
        int row = idx >> 3, c8 = idx & 7;
        *(half8*)(&T[row * 72 + c8 * 8]) =
            *(const half8*)(V + ((size_t)bh * SEQ + z0 + row) * HD + c8 * 8);
    }
    __syncthreads();
    #pragma unroll
    for (int it = 0; it < 4; ++it) {
        int idx = tid + (it << 8);
        int d = idx >> 4, c4 = idx & 15;
        unsigned short a = T[(c4 * 4 + 0) * 72 + d];
        unsigned short b = T[(c4 * 4 + 1) * 72 + d];
        unsigned short c = T[(c4 * 4 + 2) * 72 + d];
        unsigned short e = T[(c4 * 4 + 3) * 72 + d];
        uint2 o = make_uint2((unsigned)a | ((unsigned)b << 16),
                             (unsigned)c | ((unsigned)e << 16));
        *(uint2*)(Vt + ((size_t)bh * HD + d) * SEQ + z0 + (c4 << 2)) = o;
    }
}

// ---------------------------------------------------------------------------
// Flash attention, transposed-S, paired s-tiles sharing staged K/V.
// VALU-cut round: row sums via ones-A MFMA (in P's f16 precision — cancels
// quantization in P/sum ratio), cvt_pkrtz packed P conversion, vectorized
// exp argument. Row 0 patched analytically from Vsum.
// ---------------------------------------------------------------------------
__global__ __launch_bounds__(256) void attn_kernel(
    const unsigned short* __restrict__ Qg, const unsigned short* __restrict__ Kg,
    const unsigned short* __restrict__ Vtg, const float* __restrict__ Vsum,
    unsigned short* __restrict__ Og)
{
    __shared__ unsigned short Kl[64 * LK];   // K tile [z][d]
    __shared__ unsigned short Vl[64 * LK];   // Vt tile [d][z]

    const int tid  = threadIdx.x;
    const int w    = tid >> 6;
    const int lane = tid & 63;
    const int q    = lane >> 4;
    const int l    = lane & 15;

    const int bid = blockIdx.x;
    const int bh  = bid & (BH - 1);
    const int p   = bid >> 5;              // 0..15, heavy (p=0) first
    const int stA = 31 - p;
    const int stB = p;
    const int ntB = p + 1;
    const int sweep = stA + 1;

    const unsigned short* Qb  = Qg  + (size_t)bh * SEQ * HD;
    const unsigned short* Kb  = Kg  + (size_t)bh * SEQ * HD;
    const unsigned short* Vtb = Vtg + (size_t)bh * HD * SEQ;

    const int s_colA = (stA << 6) + 16 * w + l;
    const int s_colB = (stB << 6) + 16 * w + l;

    half8 qBA[2], qBB[2];
    {
        const unsigned short* qp = Qb + (size_t)s_colA * HD + 8 * q;
        qBA[0] = *(const half8*)(qp);
        qBA[1] = *(const half8*)(qp + 32);
        qp = Qb + (size_t)s_colB * HD + 8 * q;
        qBB[0] = *(const half8*)(qp);
        qBB[1] = *(const half8*)(qp + 32);
    }

    half4 onesA;
    #pragma unroll
    for (int j = 0; j < 4; ++j) onesA[j] = (_Float16)1.0f;

    float m_runA = -INFINITY, l_runA = 0.f;
    float m_runB = -INFINITY, l_runB = 0.f;
    floatx4 oaccA[4], oaccB[4];
    #pragma unroll
    for (int nd = 0; nd < 4; ++nd) {
        oaccA[nd] = (floatx4){0.f, 0.f, 0.f, 0.f};
        oaccB[nd] = (floatx4){0.f, 0.f, 0.f, 0.f};
    }

    for (int zt = 0; zt < sweep; ++zt) {
        const int z0 = zt << 6;
        __syncthreads();
        #pragma unroll
        for (int it = 0; it < 2; ++it) {
            int idx = tid + (it << 8);
            int row = idx >> 3, c8 = idx & 7;
            *(half8*)(&Kl[row * LK + c8 * 8]) =
                *(const half8*)(Kb + (size_t)(z0 + row) * HD + c8 * 8);
            *(half8*)(&Vl[row * LK + c8 * 8]) =
                *(const half8*)(Vtb + (size_t)row * SEQ + z0 + c8 * 8);
        }
        __syncthreads();

        const bool bact = (zt < ntB);

        // S^T for both groups from SHARED K A-frags
        floatx4 saccA[4], saccB[4];
        #pragma unroll
        for (int t = 0; t < 4; ++t) {
            saccA[t] = (floatx4){0.f, 0.f, 0.f, 0.f};
            saccB[t] = (floatx4){0.f, 0.f, 0.f, 0.f};
            half8 aK0 = *(const half8*)(&Kl[(16 * t + l) * LK + 8 * q]);
            half8 aK1 = *(const half8*)(&Kl[(16 * t + l) * LK + 8 * q + 32]);
            saccA[t] = __builtin_amdgcn_mfma_f32_16x16x32_f16(aK0, qBA[0], saccA[t], 0, 0, 0);
            saccA[t] = __builtin_amdgcn_mfma_f32_16x16x32_f16(aK1, qBA[1], saccA[t], 0, 0, 0);
            if (bact) {
                saccB[t] = __builtin_amdgcn_mfma_f32_16x16x32_f16(aK0, qBB[0], saccB[t], 0, 0, 0);
                saccB[t] = __builtin_amdgcn_mfma_f32_16x16x32_f16(aK1, qBB[1], saccB[t], 0, 0, 0);
            }
        }

        // masks (diag tiles only; group A never contains row 0)
        if (zt == stA) {
            #pragma unroll
            for (int t = 0; t < 4; ++t)
                #pragma unroll
                for (int r = 0; r < 4; ++r) {
                    int z = z0 + 16 * t + 4 * q + r;
                    if (z >= s_colA) saccA[t][r] = -1e12f;
                }
        }
        if (bact && zt == stB) {
            float mval = (s_colB == 0) ? 0.0f : -1e12f;
            #pragma unroll
            for (int t = 0; t < 4; ++t)
                #pragma unroll
                for (int r = 0; r < 4; ++r) {
                    int z = z0 + 16 * t + 4 * q + r;
                    if (z >= s_colB) saccB[t][r] = mval;
                }
        }

        // online softmax, scalar-per-lane; sums via ones-MFMA
        half4 pBA[4], pBB[4];
        {
            float rm = -INFINITY;
            #pragma unroll
            for (int t = 0; t < 4; ++t)
                #pragma unroll
                for (int r = 0; r < 4; ++r) rm = fmaxf(rm, saccA[t][r]);
            rm = fmaxf(rm, __shfl_xor(rm, 16, 64));
            rm = fmaxf(rm, __shfl_xor(rm, 32, 64));
            float mn = fmaxf(m_runA, rm);
            floatx4 mnv = (floatx4){mn, mn, mn, mn};
            #pragma unroll
            for (int t = 0; t < 4; ++t) {
                floatx4 e = saccA[t] - mnv;
                union { half4 v; half2t h[2]; } u;
                u.h[0] = cvt_pk(EXP2(e[0]), EXP2(e[1]));
                u.h[1] = cvt_pk(EXP2(e[2]), EXP2(e[3]));
                pBA[t] = u.v;
            }
            floatx4 ls = (floatx4){0.f, 0.f, 0.f, 0.f};
            #pragma unroll
            for (int t = 0; t < 4; ++t)
                ls = __builtin_amdgcn_mfma_f32_16x16x16f16(onesA, pBA[t], ls, 0, 0, 0);
            float alpha = EXP2(m_runA - mn);
            l_runA = alpha * l_runA + ls[0];
            m_runA = mn;
            #pragma unroll
            for (int nd = 0; nd < 4; ++nd) oaccA[nd] *= alpha;
        }
        if (bact) {
            float rm = -INFINITY;
            #pragma unroll
            for (int t = 0; t < 4; ++t)
                #pragma unroll
                for (int r = 0; r < 4; ++r) rm = fmaxf(rm, saccB[t][r]);
            rm = fmaxf(rm, __shfl_xor(rm, 16, 64));
            rm = fmaxf(rm, __shfl_xor(rm, 32, 64));
            float mn = fmaxf(m_runB, rm);
            floatx4 mnv = (floatx4){mn, mn, mn, mn};
            #pragma unroll
            for (int t = 0; t < 4; ++t) {
                floatx4 e = saccB[t] - mnv;
                union { half4 v; half2t h[2]; } u;
                u.h[0] = cvt_pk(EXP2(e[0]), EXP2(e[1]));
                u.h[1] = cvt_pk(EXP2(e[2]), EXP2(e[3]));
                pBB[t] = u.v;
            }
            floatx4 ls = (floatx4){0.f, 0.f, 0.f, 0.f};
            #pragma unroll
            for (int t = 0; t < 4; ++t)
                ls = __builtin_amdgcn_mfma_f32_16x16x16f16(onesA, pBB[t], ls, 0, 0, 0);
            float alpha = EXP2(m_runB - mn);
            l_runB = alpha * l_runB + ls[0];
            m_runB = mn;
            #pragma unroll
            for (int nd = 0; nd < 4; ++nd) oaccB[nd] *= alpha;
        }

        // O^T += V^T P^T : V A-frags read ONCE, feed both groups
        #pragma unroll
        for (int t = 0; t < 4; ++t)
            #pragma unroll
            for (int nd = 0; nd < 4; ++nd) {
                half4 vA = *(const half4*)(&Vl[(16 * nd + l) * LK + 16 * t + 4 * q]);
                oaccA[nd] = __builtin_amdgcn_mfma_f32_16x16x16f16(vA, pBA[t], oaccA[nd], 0, 0, 0);
                if (bact)
                    oaccB[nd] = __builtin_amdgcn_mfma_f32_16x16x16f16(vA, pBB[t], oaccB[nd], 0, 0, 0);
            }
    }

    // epilogue
    const int b = bh >> 4, h = bh & 15;
    {
        float inv = 1.0f / l_runA;
        unsigned short* op = Og + ((size_t)b * SEQ + s_colA) * FDIM + h * HD;
        #pragma unroll
        for (int nd = 0; nd < 4; ++nd) {
            uint2 o = make_uint2(pk_f16(oaccA[nd][0] * inv, oaccA[nd][1] * inv),
                                 pk_f16(oaccA[nd][2] * inv, oaccA[nd][3] * inv));
            *(uint2*)(op + 16 * nd + 4 * q) = o;
        }
    }
    {
        float inv = 1.0f / l_runB;
        if (s_colB == 0) {                 // row 0: O = mean(V), analytically
            inv = 1.0f / 2048.0f;
            #pragma unroll
            for (int nd = 0; nd < 4; ++nd) {
                float4 vs = *(const float4*)(Vsum + bh * 64 + 16 * nd + 4 * q);
                oaccB[nd] = (floatx4){vs.x, vs.y, vs.z, vs.w};
            }
        }
        unsigned short* op = Og + ((size_t)b * SEQ + s_colB) * FDIM + h * HD;
        #pragma unroll
        for (int nd = 0; nd < 4; ++nd) {
            uint2 o = make_uint2(pk_f16(oaccB[nd][0] * inv, oaccB[nd][1] * inv),
                                 pk_f16(oaccB[nd][2] * inv, oaccB[nd][3] * inv));
            *(uint2*)(op + 16 * nd + 4 * q) = o;
        }
    }
}

// ---------------------------------------------------------------------------
extern "C" void kernel_launch(void* const* d_in, const int* in_sizes, int n_in,
                              void* d_out, int out_size, void* d_ws, size_t ws_size,
                              hipStream_t stream) {
    const float* attend_from = (const float*)d_in[0];
    const float* attend_to   = (const float*)d_in[1];
    const float* w_q   = (const float*)d_in[2];
    const float* b_q   = (const float*)d_in[3];
    const float* w_kv  = (const float*)d_in[4];
    const float* b_kv  = (const float*)d_in[5];
    const float* w_out = (const float*)d_in[6];
    const float* b_out = (const float*)d_in[7];
    float* out = (float*)d_out;

    unsigned short* ws = (unsigned short*)d_ws;
    const size_t E = (size_t)(SB * SEQ) * FDIM;   // 4M elems
    unsigned short* Af   = ws;
    unsigned short* At   = ws + E;
    unsigned short* Qb   = ws + 2 * E;
    unsigned short* Kb   = ws + 3 * E;
    unsigned short* Vb   = ws + 4 * E;
    unsigned short* Vt   = ws + 5 * E;
    unsigned short* Ob   = Vb;                    // reuse V after transpose
    unsigned short* Wqt  = ws + 6 * E;
    unsigned short* Wkvt = ws + 6 * E + E / 4;
    unsigned short* Wot  = ws + 6 * E + E / 4 + E / 2;
    float*          Vsum = (float*)(ws + 7 * E);  // 2048 fp32

    dim3 blk(256);
    const int M = SB * SEQ;   // 4096

    cvt_all<<<dim3(5120), blk, 0, stream>>>(
        attend_from, attend_to, Af, At, w_q, w_kv, w_out, Wqt, Wkvt, Wot);
    gemm_qkv<<<dim3(24, M / 128), blk, 0, stream>>>(
        Af, At, Wqt, Wkvt, b_q, b_kv, Qb, Kb, Vb);
    transpose_v<<<dim3(1024 + BH), blk, 0, stream>>>(Vb, Vt, Vsum);
    attn_kernel<<<dim3(BH * 16), blk, 0, stream>>>(Qb, Kb, Vt, Vsum, Ob);
    gemm_out<<<dim3(FDIM / 128, M / 64), blk, 0, stream>>>(Ob, Wot, b_out, out);
}